// Round 7
// baseline (1014.903 us; speedup 1.0000x reference)
//
#include <hip/hip_runtime.h>
#include <hip/hip_bf16.h>
#include <math.h>

// ConvBlockFD R9 = R8 (verified 926us) with conv rebuilt on mfma_f32_32x32x16_bf16.
// Why: R8 conv2 at 46% of 2495TF with all BW far from roofs -> MFMA pipe + issue
// bound at 2 waves/SIMD. 32x32x16 runs ~15-17% faster than 16x16x32 (m119: 2495 vs
// 2176 TF) and halves instruction count (144 vs 288 MFMA/wave-kc).
// - Block tile: 32 cols x 8 rows x 256 co; 8 waves = 4 co-blocks(64) x 2 row-grps(4).
// - M-tile = 1 spatial row x 32 px: A/B frag m/n = lane&31, k = (lane>>5)*8+j;
//   D row = (reg&3)+8*(reg>>2)+4*(lane>>5) (verified m74/m101).
// - LDS chunk-major [4 ci-chunks][346 pad][16B]: xf reads 512B-contiguous per
//   half-wave (conflict-free); staging writes land on bank-quads stride 8 (free).
// - acc 2x4xf32x16 = 128 AGPR; VGPR target <=128 to keep 2 waves/SIMD.
// Aux kernels unchanged from R7/R8.

#define K_NUM 4
typedef __attribute__((ext_vector_type(8))) short short8;    // 8 bf16 = 4 VGPR
typedef __attribute__((ext_vector_type(4))) float f32x4;
typedef __attribute__((ext_vector_type(16))) float f32x16;   // 32x32 MFMA C/D

__device__ inline float bf2f(short s) {
  unsigned u = ((unsigned)(unsigned short)s) << 16;
  return __uint_as_float(u);
}
__device__ inline short f2bf(float f) {
  __hip_bfloat16 h = __float2bfloat16(f);
  return (short)*reinterpret_cast<unsigned short*>(&h);
}

// ---------------- partial-sum reduce: gap[row] = scale * sum(part[row][0..4*n4)) ----
__global__ __launch_bounds__(256) void gap_reduce_kernel(
    const float* __restrict__ part, float* __restrict__ gap, float scale, int n4) {
  int row = blockIdx.x * 4 + (threadIdx.x >> 6);
  int lane = threadIdx.x & 63;
  float4 v = {0.f, 0.f, 0.f, 0.f};
  if (lane < n4) v = *(const float4*)(part + (size_t)row * 256 + lane * 4);
  float s = v.x + v.y + v.z + v.w;
#pragma unroll
  for (int m = 1; m <= 32; m <<= 1) s += __shfl_xor(s, m, 64);
  if (lane == 0) gap[row] = s * scale;
}

// ---------------- attention MLP + softmax ----------------
__global__ void fd_attn_kernel(const float* __restrict__ gap, int C, int Hd,
                               const float* __restrict__ w1, const float* __restrict__ b1,
                               const float* __restrict__ w2, const float* __restrict__ b2,
                               float* __restrict__ attn) {
  int b = blockIdx.x, j = threadIdx.x;
  __shared__ float h[64];
  __shared__ float z[K_NUM];
  if (j < Hd) {
    float s = b1[j];
    const float* g = gap + (size_t)b * C;
    for (int c = 0; c < C; ++c) s = fmaf(g[c], w1[c * Hd + j], s);
    h[j] = fmaxf(s, 0.f);
  }
  __syncthreads();
  if (j < K_NUM) {
    float s = b2[j];
    for (int c = 0; c < Hd; ++c) s = fmaf(h[c], w2[c * K_NUM + j], s);
    z[j] = s;
  }
  __syncthreads();
  if (j == 0) {
    float m = z[0];
    for (int k = 1; k < K_NUM; ++k) m = fmaxf(m, z[k]);
    float e[K_NUM], sum = 0.f;
    for (int k = 0; k < K_NUM; ++k) { e[k] = expf(z[k] - m); sum += e[k]; }
    for (int k = 0; k < K_NUM; ++k) attn[b * K_NUM + k] = e[k] / sum;
  }
}

// ---------------- synthesis: irfft2 + attention mix -> wd_t[b][9][ci/8][co][8] bf16 ----
__global__ void fd_synth_t_kernel(const float* __restrict__ wfr, const float* __restrict__ wfi,
                                  const float* __restrict__ attn, short* __restrict__ wdt,
                                  int B, int CO, int CI) {
  size_t gid = (size_t)blockIdx.x * blockDim.x + threadIdx.x;
  size_t total = (size_t)B * CI * CO;
  if (gid >= total) return;
  int ci = (int)(gid % CI);
  size_t t = gid / CI;
  int co = (int)(t % CO);
  int b = (int)(t / CO);

  float a[K_NUM];
  for (int k = 0; k < K_NUM; ++k) a[k] = attn[b * K_NUM + k];

  float Fr[3][2], Fi[3][2];
  for (int u = 0; u < 3; ++u) for (int v = 0; v < 2; ++v) { Fr[u][v] = 0.f; Fi[u][v] = 0.f; }
  for (int k = 0; k < K_NUM; ++k) {
    size_t base = ((((size_t)k * CO + co) * CI + ci) * 3) * 2;
    const float* pr = wfr + base;
    const float* pi = wfi + base;
    float ak = a[k];
    for (int u = 0; u < 3; ++u)
      for (int v = 0; v < 2; ++v) {
        Fr[u][v] = fmaf(ak, pr[u * 2 + v], Fr[u][v]);
        Fi[u][v] = fmaf(ak, pi[u * 2 + v], Fi[u][v]);
      }
  }

  const float CS[3] = {1.f, -0.5f, -0.5f};
  const float SN[3] = {0.f, 0.8660254037844386f, -0.8660254037844386f};
  float outv[9];
  for (int ai = 0; ai < 3; ++ai) {
    float Gr[2], Gi[2];
    for (int v = 0; v < 2; ++v) {
      float gr = 0.f, gi = 0.f;
      for (int u = 0; u < 3; ++u) {
        int idx = (u * ai) % 3;
        gr += Fr[u][v] * CS[idx] - Fi[u][v] * SN[idx];
        gi += Fr[u][v] * SN[idx] + Fi[u][v] * CS[idx];
      }
      Gr[v] = gr * (1.f / 3.f);
      Gi[v] = gi * (1.f / 3.f);
    }
    for (int bi = 0; bi < 3; ++bi)
      outv[ai * 3 + bi] = (Gr[0] + 2.f * (Gr[1] * CS[bi] - Gi[1] * SN[bi])) * (1.f / 3.f);
  }
  int ci8 = ci >> 3, cil = ci & 7;
  for (int s = 0; s < 9; ++s)
    wdt[((((size_t)b * 9 + s) * (CI / 8) + ci8) * CO + co) * 8 + cil] = f2bf(outv[s]);
}

// ---------------- transpose fp32 NCHW -> bf16 channels-last + layer-1 GAP partials ----
__global__ __launch_bounds__(256) void transpose_bf16_kernel(
    const float* __restrict__ in, short* __restrict__ out, int C,
    float* __restrict__ gpart1) {   // [B*C][256] per-pxblock partials
  const int HW = 16384;
  __shared__ short t[64 * 40];
  int tid = threadIdx.x;
  int px0 = blockIdx.x * 64, c0 = blockIdx.y * 32, b = blockIdx.z;
  int px = tid & 63, cb = tid >> 6;   // wave cb handles c = {cb, 4+cb, ..., 28+cb}
  float sums[8];
#pragma unroll
  for (int i = 0; i < 8; ++i) {
    int c = i * 4 + cb;
    float v = in[((size_t)b * C + c0 + c) * HW + px0 + px];
    t[px * 40 + c] = f2bf(v);
    sums[i] = v;
  }
  __syncthreads();
  int px2 = tid >> 2, g = tid & 3;
  short8 v = *(const short8*)(t + px2 * 40 + g * 8);
  *(short8*)(out + ((size_t)b * HW + px0 + px2) * C + c0 + g * 8) = v;
  // per-wave channel partials over 64 px (no atomics)
#pragma unroll
  for (int m = 1; m <= 32; m <<= 1)
#pragma unroll
    for (int i = 0; i < 8; ++i) sums[i] += __shfl_xor(sums[i], m, 64);
  if ((tid & 63) == 0)
#pragma unroll
    for (int i = 0; i < 8; ++i)
      gpart1[((size_t)b * C + c0 + i * 4 + cb) * 256 + blockIdx.x] = sums[i];
}

// ---------------- MFMA conv: 9 shift-GEMMs, 32x32x16 bf16, 2-phase dbuf ----------
// Block: 512 threads = 8 waves: wc = w>>1 (4 co-blocks of 64), wy = w&1 (row grp of 4).
// Spatial tile: 32 cols x 8 rows (tx0 = (bx&3)*32, ty0 = (bx>>2)*8); halo 34x10.
// LDS: chunk-major [4 ci-chunks][NPXP=346][16B] per buffer, double-buffered.
// Frags: m/n = lane&31, k-half = lane>>5. acc[4 nf][2 ncf] f32x16.
// MODE 0 (conv1): mfma(xf,wf) -> D[px][co], bf16 channels-last + GAP partials.
// MODE 1 (conv2): mfma(wf,xf) -> D[co][px], fp32 NCHW.
template <int CI, int MODE>
__global__ __launch_bounds__(512, 2) void conv_mfma_kernel(
    const short* __restrict__ xin,   // [B][HW][CI] bf16
    const short* __restrict__ wdt,   // [B][9][CI/8][256][8] bf16
    const float* __restrict__ bias,  // [256]
    short* __restrict__ yout_t,      // MODE0 out
    float* __restrict__ yout_f,      // MODE1 out
    float* __restrict__ gpart2) {    // MODE0: [B*256][256] GAP partials (128 used)
  const int H = 128, W = 128, HW = H * W, CO = 256;
  const int NKC = CI / 32;
  const int NPX = 340;               // 10 rows x 34 cols
  const int NPXP = 346;              // 16B units row-pad (bank-quad stride 8)
  __shared__ short xs[2][4 * NPXP * 8];  // 2 x 22144 B

  const int tid = threadIdx.x;
  const int w = tid >> 6;
  const int wy = w & 1, wc = w >> 1;
  const int lane = tid & 63;
  const int l31 = lane & 31;
  const int h = lane >> 5;           // k-half
  const int tx0 = (blockIdx.x & 3) * 32, ty0 = (blockIdx.x >> 2) * 8;
  const int cob = wc * 64;
  const int b = blockIdx.z;

  // staging coords: thread tid (<340) owns halo px p; loads its 4 ci-chunks (64B)
  const int sp = tid;
  const int srr = sp / 34, scc = sp - srr * 34;
  const int sgy = ty0 + srr - 1, sgx = tx0 + scc - 1;
  const bool sok = (tid < NPX);
  const bool sin = sok && (unsigned)sgy < (unsigned)H && (unsigned)sgx < (unsigned)W;
  const short* sgp = xin + ((size_t)b * HW + sgy * W + sgx) * CI;

  short8 pre[4];
  auto stage_load = [&](int kc) {
#pragma unroll
    for (int g = 0; g < 4; ++g) {
      short8 v = {0, 0, 0, 0, 0, 0, 0, 0};
      if (sin) v = *(const short8*)(sgp + kc * 32 + g * 8);
      pre[g] = v;
    }
  };
  auto stage_write = [&](short* buf) {
    if (sok) {
#pragma unroll
      for (int g = 0; g < 4; ++g)
        *(short8*)(buf + (g * NPXP + sp) * 8) = pre[g];
    }
  };

  f32x16 acc[4][2];
#pragma unroll
  for (int i = 0; i < 4; ++i)
#pragma unroll
    for (int j = 0; j < 2; ++j)
#pragma unroll
      for (int r = 0; r < 16; ++r) acc[i][j][r] = 0.f;

  // prologue: fill buf 0
  stage_load(0);
  stage_write(xs[0]);
  __syncthreads();

  int cur = 0;
  for (int kc = 0; kc < NKC; ++kc) {
    const bool more = (kc + 1 < NKC);
    if (more) stage_load(kc + 1);        // issue early; latency hides under MFMA
    const short* bufc = xs[cur];

#pragma unroll
    for (int dc = 0; dc < 3; ++dc) {
#pragma unroll
      for (int ks = 0; ks < 2; ++ks) {
        // x frags: 6 halo rows cover nf(0..3)+dr(0..2); 512B-contig per half-wave
        short8 xf[6];
#pragma unroll
        for (int rr = 0; rr < 6; ++rr) {
          int p = (wy * 4 + rr) * 34 + l31 + dc;
          xf[rr] = *(const short8*)(bufc + ((ks * 2 + h) * NPXP + p) * 8);
        }
#pragma unroll
        for (int dr = 0; dr < 3; ++dr) {
          short8 wf[2];
          const short* wp = wdt + ((((size_t)b * 9 + dr * 3 + dc) * (CI / 8) + kc * 4 + ks * 2 + h) * CO + cob + l31) * 8;
#pragma unroll
          for (int ncf = 0; ncf < 2; ++ncf)
            wf[ncf] = *(const short8*)(wp + ncf * 32 * 8);
#pragma unroll
          for (int nf = 0; nf < 4; ++nf)
#pragma unroll
            for (int ncf = 0; ncf < 2; ++ncf) {
              if (MODE == 0)
                acc[nf][ncf] = __builtin_amdgcn_mfma_f32_32x32x16_bf16(
                    xf[nf + dr], wf[ncf], acc[nf][ncf], 0, 0, 0);
              else
                acc[nf][ncf] = __builtin_amdgcn_mfma_f32_32x32x16_bf16(
                    wf[ncf], xf[nf + dr], acc[nf][ncf], 0, 0, 0);
            }
        }
      }
    }

    if (more) stage_write(xs[cur ^ 1]);  // compiler inserts vmcnt wait on pre[]
    __syncthreads();                     // one barrier per kc
    cur ^= 1;
  }

  if (MODE == 0) {
    // D[m=px-col][n=co]: n = l31 (co), m = (reg&3)+8*(reg>>2)+4*h (px col)
    float gs[2] = {0.f, 0.f};
#pragma unroll
    for (int ncf = 0; ncf < 2; ++ncf) {
      int co = cob + ncf * 32 + l31;
      float bs = bias[co];
#pragma unroll
      for (int nf = 0; nf < 4; ++nf) {
        int row = ty0 + wy * 4 + nf;
#pragma unroll
        for (int reg = 0; reg < 16; ++reg) {
          int mcol = (reg & 3) + 8 * (reg >> 2) + 4 * h;
          int col = tx0 + mcol;
          float v = fmaxf(acc[nf][ncf][reg] + bs, 0.f);
          gs[ncf] += v;
          yout_t[((size_t)b * HW + (size_t)row * W + col) * CO + co] = f2bf(v);
        }
      }
    }
    // lanes l and l+32 share co; reduce then lanes<32 write partials
#pragma unroll
    for (int ncf = 0; ncf < 2; ++ncf) gs[ncf] += __shfl_xor(gs[ncf], 32, 64);
    if (lane < 32) {
      int pslot = blockIdx.x * 2 + wy;   // 64 px-blocks x 2 row-groups = 128 slots
#pragma unroll
      for (int ncf = 0; ncf < 2; ++ncf)
        gpart2[((size_t)b * 256 + cob + ncf * 32 + lane) * 256 + pslot] = gs[ncf];
    }
  } else {
    // D[m=co][n=px-col]: n = l31 (px col), m = (reg&3)+8*(reg>>2)+4*h (co)
#pragma unroll
    for (int ncf = 0; ncf < 2; ++ncf) {
#pragma unroll
      for (int reg = 0; reg < 16; ++reg) {
        int co = cob + ncf * 32 + (reg & 3) + 8 * (reg >> 2) + 4 * h;
        float bs = bias[co];
#pragma unroll
        for (int nf = 0; nf < 4; ++nf) {
          int row = ty0 + wy * 4 + nf;
          yout_f[((size_t)b * CO + co) * HW + (size_t)row * W + tx0 + l31] =
              fmaxf(acc[nf][ncf][reg] + bs, 0.f);
        }
      }
    }
  }
}

extern "C" void kernel_launch(void* const* d_in, const int* in_sizes, int n_in,
                              void* d_out, int out_size, void* d_ws, size_t ws_size,
                              hipStream_t stream) {
  const int B = 16, CIN = 128, COUT = 256, H = 128, W = 128, HW = H * W;

  const float* x    = (const float*)d_in[0];
  const float* w1fr = (const float*)d_in[1];
  const float* w1fi = (const float*)d_in[2];
  const float* b1   = (const float*)d_in[3];
  const float* a1w1 = (const float*)d_in[4];
  const float* a1b1 = (const float*)d_in[5];
  const float* a1w2 = (const float*)d_in[6];
  const float* a1b2 = (const float*)d_in[7];
  const float* w2fr = (const float*)d_in[8];
  const float* w2fi = (const float*)d_in[9];
  const float* b2   = (const float*)d_in[10];
  const float* a2w1 = (const float*)d_in[11];
  const float* a2b1 = (const float*)d_in[12];
  const float* a2w2 = (const float*)d_in[13];
  const float* a2b2 = (const float*)d_in[14];
  float* outf = (float*)d_out;

  // d_out scratch (all dead before conv2 overwrites d_out):
  short* xt     = (short*)d_out;                              // 67,108,864 B
  float* gpart1 = (float*)((char*)d_out + 67108864);          //  2,097,152 B (B*CIN x 256)
  float* gpart2 = (float*)((char*)d_out + 69206016);          //  4,194,304 B (B*COUT x 256)

  char* wsb = (char*)d_ws;
  short* y1t  = (short*)wsb;                                   // 134,217,728 B
  short* wdt  = (short*)(wsb + 134217728);                     //  18,874,368 B
  float* gap1 = (float*)(wsb + 134217728 + 18874368);          //       8,192 B
  float* gap2 = (float*)(wsb + 134217728 + 18874368 + 8192);   //      16,384 B
  float* attn = (float*)(wsb + 134217728 + 18874368 + 8192 + 16384); // 256 B

  const float gsc = 1.f / (float)HW;

  // ---- layer 1 ----
  transpose_bf16_kernel<<<dim3(HW / 64, CIN / 32, B), 256, 0, stream>>>(x, xt, CIN, gpart1);
  gap_reduce_kernel<<<(B * CIN) / 4, 256, 0, stream>>>(gpart1, gap1, gsc, 64);
  fd_attn_kernel<<<B, 64, 0, stream>>>(gap1, CIN, CIN / 4, a1w1, a1b1, a1w2, a1b2, attn);
  fd_synth_t_kernel<<<(B * CIN * COUT) / 256, 256, 0, stream>>>(w1fr, w1fi, attn, wdt, B, COUT, CIN);
  conv_mfma_kernel<128, 0><<<dim3(64, 1, 16), 512, 0, stream>>>(xt, wdt, b1, y1t, nullptr, gpart2);

  // ---- layer 2 ----
  gap_reduce_kernel<<<(B * COUT) / 4, 256, 0, stream>>>(gpart2, gap2, gsc, 32);
  fd_attn_kernel<<<B, 64, 0, stream>>>(gap2, COUT, COUT / 4, a2w1, a2b1, a2w2, a2b2, attn);
  fd_synth_t_kernel<<<(B * COUT * COUT) / 256, 256, 0, stream>>>(w2fr, w2fi, attn, wdt, B, COUT, COUT);
  conv_mfma_kernel<256, 1><<<dim3(64, 1, 16), 512, 0, stream>>>(y1t, wdt, b2, nullptr, outf, nullptr);
}

// Round 8
// 988.000 us; speedup vs baseline: 1.0272x; 1.0272x over previous
//
#include <hip/hip_runtime.h>
#include <hip/hip_bf16.h>
#include <math.h>

// ConvBlockFD R10 = R9 (32x32x16 mappings verified) + latency-fix schedule:
// - wf double-buffer: 6 b128 L2 loads per (dc,ks) group, prefetched one group
//   ahead (incl. cross-kc) -> 24 MFMA (~384 cyc @2 waves/SIMD) cover ~250cyc L2
//   latency. R9 had 8 MFMA/cover -> MfmaUtil 38%, 220us stall.
// - x staging via global_load_lds width=16 (4/thread): frees pre[] 16 VGPR +
//   ds_write VALU so wf dbuf fits under the 128-VGPR 2-wave cap. Staging is the
//   required wave-uniform-base + lane*16 pattern; OOB halo lanes point their
//   per-lane src at a zeroed 256B scratch (zeroed by hipMemsetAsync).
// Aux kernels unchanged from R7/R8/R9.

#define K_NUM 4
typedef __attribute__((ext_vector_type(8))) short short8;    // 8 bf16 = 4 VGPR
typedef __attribute__((ext_vector_type(4))) float f32x4;
typedef __attribute__((ext_vector_type(16))) float f32x16;   // 32x32 MFMA C/D

__device__ inline float bf2f(short s) {
  unsigned u = ((unsigned)(unsigned short)s) << 16;
  return __uint_as_float(u);
}
__device__ inline short f2bf(float f) {
  __hip_bfloat16 h = __float2bfloat16(f);
  return (short)*reinterpret_cast<unsigned short*>(&h);
}

__device__ inline void gll16(const void* g, void* l) {
  __builtin_amdgcn_global_load_lds(g, l, 16, 0, 0);
}

// ---------------- partial-sum reduce: gap[row] = scale * sum(part[row][0..4*n4)) ----
__global__ __launch_bounds__(256) void gap_reduce_kernel(
    const float* __restrict__ part, float* __restrict__ gap, float scale, int n4) {
  int row = blockIdx.x * 4 + (threadIdx.x >> 6);
  int lane = threadIdx.x & 63;
  float4 v = {0.f, 0.f, 0.f, 0.f};
  if (lane < n4) v = *(const float4*)(part + (size_t)row * 256 + lane * 4);
  float s = v.x + v.y + v.z + v.w;
#pragma unroll
  for (int m = 1; m <= 32; m <<= 1) s += __shfl_xor(s, m, 64);
  if (lane == 0) gap[row] = s * scale;
}

// ---------------- attention MLP + softmax ----------------
__global__ void fd_attn_kernel(const float* __restrict__ gap, int C, int Hd,
                               const float* __restrict__ w1, const float* __restrict__ b1,
                               const float* __restrict__ w2, const float* __restrict__ b2,
                               float* __restrict__ attn) {
  int b = blockIdx.x, j = threadIdx.x;
  __shared__ float h[64];
  __shared__ float z[K_NUM];
  if (j < Hd) {
    float s = b1[j];
    const float* g = gap + (size_t)b * C;
    for (int c = 0; c < C; ++c) s = fmaf(g[c], w1[c * Hd + j], s);
    h[j] = fmaxf(s, 0.f);
  }
  __syncthreads();
  if (j < K_NUM) {
    float s = b2[j];
    for (int c = 0; c < Hd; ++c) s = fmaf(h[c], w2[c * K_NUM + j], s);
    z[j] = s;
  }
  __syncthreads();
  if (j == 0) {
    float m = z[0];
    for (int k = 1; k < K_NUM; ++k) m = fmaxf(m, z[k]);
    float e[K_NUM], sum = 0.f;
    for (int k = 0; k < K_NUM; ++k) { e[k] = expf(z[k] - m); sum += e[k]; }
    for (int k = 0; k < K_NUM; ++k) attn[b * K_NUM + k] = e[k] / sum;
  }
}

// ---------------- synthesis: irfft2 + attention mix -> wd_t[b][9][ci/8][co][8] bf16 ----
__global__ void fd_synth_t_kernel(const float* __restrict__ wfr, const float* __restrict__ wfi,
                                  const float* __restrict__ attn, short* __restrict__ wdt,
                                  int B, int CO, int CI) {
  size_t gid = (size_t)blockIdx.x * blockDim.x + threadIdx.x;
  size_t total = (size_t)B * CI * CO;
  if (gid >= total) return;
  int ci = (int)(gid % CI);
  size_t t = gid / CI;
  int co = (int)(t % CO);
  int b = (int)(t / CO);

  float a[K_NUM];
  for (int k = 0; k < K_NUM; ++k) a[k] = attn[b * K_NUM + k];

  float Fr[3][2], Fi[3][2];
  for (int u = 0; u < 3; ++u) for (int v = 0; v < 2; ++v) { Fr[u][v] = 0.f; Fi[u][v] = 0.f; }
  for (int k = 0; k < K_NUM; ++k) {
    size_t base = ((((size_t)k * CO + co) * CI + ci) * 3) * 2;
    const float* pr = wfr + base;
    const float* pi = wfi + base;
    float ak = a[k];
    for (int u = 0; u < 3; ++u)
      for (int v = 0; v < 2; ++v) {
        Fr[u][v] = fmaf(ak, pr[u * 2 + v], Fr[u][v]);
        Fi[u][v] = fmaf(ak, pi[u * 2 + v], Fi[u][v]);
      }
  }

  const float CS[3] = {1.f, -0.5f, -0.5f};
  const float SN[3] = {0.f, 0.8660254037844386f, -0.8660254037844386f};
  float outv[9];
  for (int ai = 0; ai < 3; ++ai) {
    float Gr[2], Gi[2];
    for (int v = 0; v < 2; ++v) {
      float gr = 0.f, gi = 0.f;
      for (int u = 0; u < 3; ++u) {
        int idx = (u * ai) % 3;
        gr += Fr[u][v] * CS[idx] - Fi[u][v] * SN[idx];
        gi += Fr[u][v] * SN[idx] + Fi[u][v] * CS[idx];
      }
      Gr[v] = gr * (1.f / 3.f);
      Gi[v] = gi * (1.f / 3.f);
    }
    for (int bi = 0; bi < 3; ++bi)
      outv[ai * 3 + bi] = (Gr[0] + 2.f * (Gr[1] * CS[bi] - Gi[1] * SN[bi])) * (1.f / 3.f);
  }
  int ci8 = ci >> 3, cil = ci & 7;
  for (int s = 0; s < 9; ++s)
    wdt[((((size_t)b * 9 + s) * (CI / 8) + ci8) * CO + co) * 8 + cil] = f2bf(outv[s]);
}

// ---------------- transpose fp32 NCHW -> bf16 channels-last + layer-1 GAP partials ----
__global__ __launch_bounds__(256) void transpose_bf16_kernel(
    const float* __restrict__ in, short* __restrict__ out, int C,
    float* __restrict__ gpart1) {   // [B*C][256] per-pxblock partials
  const int HW = 16384;
  __shared__ short t[64 * 40];
  int tid = threadIdx.x;
  int px0 = blockIdx.x * 64, c0 = blockIdx.y * 32, b = blockIdx.z;
  int px = tid & 63, cb = tid >> 6;   // wave cb handles c = {cb, 4+cb, ..., 28+cb}
  float sums[8];
#pragma unroll
  for (int i = 0; i < 8; ++i) {
    int c = i * 4 + cb;
    float v = in[((size_t)b * C + c0 + c) * HW + px0 + px];
    t[px * 40 + c] = f2bf(v);
    sums[i] = v;
  }
  __syncthreads();
  int px2 = tid >> 2, g = tid & 3;
  short8 v = *(const short8*)(t + px2 * 40 + g * 8);
  *(short8*)(out + ((size_t)b * HW + px0 + px2) * C + c0 + g * 8) = v;
  // per-wave channel partials over 64 px (no atomics)
#pragma unroll
  for (int m = 1; m <= 32; m <<= 1)
#pragma unroll
    for (int i = 0; i < 8; ++i) sums[i] += __shfl_xor(sums[i], m, 64);
  if ((tid & 63) == 0)
#pragma unroll
    for (int i = 0; i < 8; ++i)
      gpart1[((size_t)b * C + c0 + i * 4 + cb) * 256 + blockIdx.x] = sums[i];
}

// ---------------- MFMA conv: 9 shift-GEMMs, 32x32x16 bf16, dbuf + wf pipeline ----
// Block: 512 threads = 8 waves: wc = w>>1 (4 co-blocks of 64), wy = w&1 (row grp of 4).
// Spatial tile: 32 cols x 8 rows (tx0 = (bx&3)*32, ty0 = (bx>>2)*8); halo 34x10.
// LDS: chunk-major [4 ci-chunks][NPXP=346][16B] per buffer, double-buffered,
//   filled via global_load_lds (wave-uniform base + lane*16).
// wf: double-buffered regs, 6 loads per (dc,ks) group, prefetched 1 group ahead.
// Frags: m/n = lane&31, k-half = lane>>5. acc[4 nf][2 ncf] f32x16.
// MODE 0 (conv1): mfma(xf,wf) -> D[px][co], bf16 channels-last + GAP partials.
// MODE 1 (conv2): mfma(wf,xf) -> D[co][px], fp32 NCHW.
template <int CI, int MODE>
__global__ __launch_bounds__(512, 2) void conv_mfma_kernel(
    const short* __restrict__ xin,   // [B][HW][CI] bf16
    const short* __restrict__ wdt,   // [B][9][CI/8][256][8] bf16
    const float* __restrict__ bias,  // [256]
    short* __restrict__ yout_t,      // MODE0 out
    float* __restrict__ yout_f,      // MODE1 out
    float* __restrict__ gpart2,      // MODE0: [B*256][256] GAP partials (128 used)
    const short* __restrict__ zbuf) {// 256B zeroed scratch for OOB halo lanes
  const int H = 128, W = 128, HW = H * W, CO = 256;
  const int NKC = CI / 32;
  const int NPX = 340;               // 10 rows x 34 cols
  const int NPXP = 346;              // 16B units row-pad
  __shared__ short xs[2][4 * NPXP * 8];  // 2 x 22144 B

  const int tid = threadIdx.x;
  const int w = tid >> 6;
  const int wy = w & 1, wc = w >> 1;
  const int lane = tid & 63;
  const int l31 = lane & 31;
  const int h = lane >> 5;           // k-half
  const int tx0 = (blockIdx.x & 3) * 32, ty0 = (blockIdx.x >> 2) * 8;
  const int cob = wc * 64;
  const int b = blockIdx.z;

  // staging: thread tid (<340) owns halo px sp; 4 chunks of 16B via global_load_lds
  const int sp = tid;
  const int srr = sp / 34, scc = sp - srr * 34;
  const int sgy = ty0 + srr - 1, sgx = tx0 + scc - 1;
  const bool sok = (tid < NPX);
  const bool sin = sok && (unsigned)sgy < (unsigned)H && (unsigned)sgx < (unsigned)W;
  const short* sgp = xin + ((size_t)b * HW + (size_t)sgy * W + sgx) * CI;
  const int wbase = tid & ~63;       // wave-uniform LDS base px

  auto stage_issue = [&](int kc, int buf) {
    if (sok) {
#pragma unroll
      for (int g = 0; g < 4; ++g) {
        const void* src = sin ? (const void*)(sgp + kc * 32 + g * 8) : (const void*)zbuf;
        void* dst = (void*)(xs[buf] + (g * NPXP + wbase) * 8);
        gll16(src, dst);
      }
    }
  };

  const size_t drs = (size_t)3 * (CI / 8) * CO * 8;  // dr stride in wdt (shorts)
  auto load_wf = [&](short8 wfb[6], int kc, int dc, int ks) {
    const short* wp = wdt + ((((size_t)b * 9 + dc) * (CI / 8) + kc * 4 + ks * 2 + h) * CO + cob + l31) * 8;
#pragma unroll
    for (int dr = 0; dr < 3; ++dr)
#pragma unroll
      for (int ncf = 0; ncf < 2; ++ncf)
        wfb[dr * 2 + ncf] = *(const short8*)(wp + dr * drs + ncf * 256);
  };

  f32x16 acc[4][2];
#pragma unroll
  for (int i = 0; i < 4; ++i)
#pragma unroll
    for (int j = 0; j < 2; ++j)
#pragma unroll
      for (int r = 0; r < 16; ++r) acc[i][j][r] = 0.f;

  short8 wfp[2][6];

  // prologue: x buf0 + first wf group
  stage_issue(0, 0);
  load_wf(wfp[0], 0, 0, 0);
  __syncthreads();                   // drains the gll writes (vmcnt before barrier)

  int cur = 0;
  for (int kc = 0; kc < NKC; ++kc) {
    const bool more = (kc + 1 < NKC);
    if (more) stage_issue(kc + 1, cur ^ 1);   // in flight under this kc's MFMA
    const short* bufc = xs[cur];

#pragma unroll
    for (int g = 0; g < 6; ++g) {
      const int dc = g >> 1, ks = g & 1;
      // prefetch next group's wf (cross-kc at g==5)
      if (g < 5)
        load_wf(wfp[(g + 1) & 1], kc, (g + 1) >> 1, (g + 1) & 1);
      else if (more)
        load_wf(wfp[(g + 1) & 1], kc + 1, 0, 0);

      short8 xf[6];
#pragma unroll
      for (int rr = 0; rr < 6; ++rr) {
        int p = (wy * 4 + rr) * 34 + l31 + dc;
        xf[rr] = *(const short8*)(bufc + ((ks * 2 + h) * NPXP + p) * 8);
      }
#pragma unroll
      for (int dr = 0; dr < 3; ++dr)
#pragma unroll
        for (int nf = 0; nf < 4; ++nf)
#pragma unroll
          for (int ncf = 0; ncf < 2; ++ncf) {
            if (MODE == 0)
              acc[nf][ncf] = __builtin_amdgcn_mfma_f32_32x32x16_bf16(
                  xf[nf + dr], wfp[g & 1][dr * 2 + ncf], acc[nf][ncf], 0, 0, 0);
            else
              acc[nf][ncf] = __builtin_amdgcn_mfma_f32_32x32x16_bf16(
                  wfp[g & 1][dr * 2 + ncf], xf[nf + dr], acc[nf][ncf], 0, 0, 0);
          }
    }

    __syncthreads();                 // x buf for kc+1 complete; all reads of cur done
    cur ^= 1;
  }

  if (MODE == 0) {
    // D[m=px-col][n=co]: n = l31 (co), m = (reg&3)+8*(reg>>2)+4*h (px col)
    float gs[2] = {0.f, 0.f};
#pragma unroll
    for (int ncf = 0; ncf < 2; ++ncf) {
      int co = cob + ncf * 32 + l31;
      float bs = bias[co];
#pragma unroll
      for (int nf = 0; nf < 4; ++nf) {
        int row = ty0 + wy * 4 + nf;
#pragma unroll
        for (int reg = 0; reg < 16; ++reg) {
          int mcol = (reg & 3) + 8 * (reg >> 2) + 4 * h;
          int col = tx0 + mcol;
          float v = fmaxf(acc[nf][ncf][reg] + bs, 0.f);
          gs[ncf] += v;
          yout_t[((size_t)b * HW + (size_t)row * W + col) * CO + co] = f2bf(v);
        }
      }
    }
#pragma unroll
    for (int ncf = 0; ncf < 2; ++ncf) gs[ncf] += __shfl_xor(gs[ncf], 32, 64);
    if (lane < 32) {
      int pslot = blockIdx.x * 2 + wy;   // 64 px-blocks x 2 row-groups = 128 slots
#pragma unroll
      for (int ncf = 0; ncf < 2; ++ncf)
        gpart2[((size_t)b * 256 + cob + ncf * 32 + lane) * 256 + pslot] = gs[ncf];
    }
  } else {
    // D[m=co][n=px-col]: n = l31 (px col), m = (reg&3)+8*(reg>>2)+4*h (co)
#pragma unroll
    for (int ncf = 0; ncf < 2; ++ncf) {
#pragma unroll
      for (int reg = 0; reg < 16; ++reg) {
        int co = cob + ncf * 32 + (reg & 3) + 8 * (reg >> 2) + 4 * h;
        float bs = bias[co];
#pragma unroll
        for (int nf = 0; nf < 4; ++nf) {
          int row = ty0 + wy * 4 + nf;
          yout_f[((size_t)b * CO + co) * HW + (size_t)row * W + tx0 + l31] =
              fmaxf(acc[nf][ncf][reg] + bs, 0.f);
        }
      }
    }
  }
}

extern "C" void kernel_launch(void* const* d_in, const int* in_sizes, int n_in,
                              void* d_out, int out_size, void* d_ws, size_t ws_size,
                              hipStream_t stream) {
  const int B = 16, CIN = 128, COUT = 256, H = 128, W = 128, HW = H * W;

  const float* x    = (const float*)d_in[0];
  const float* w1fr = (const float*)d_in[1];
  const float* w1fi = (const float*)d_in[2];
  const float* b1   = (const float*)d_in[3];
  const float* a1w1 = (const float*)d_in[4];
  const float* a1b1 = (const float*)d_in[5];
  const float* a1w2 = (const float*)d_in[6];
  const float* a1b2 = (const float*)d_in[7];
  const float* w2fr = (const float*)d_in[8];
  const float* w2fi = (const float*)d_in[9];
  const float* b2   = (const float*)d_in[10];
  const float* a2w1 = (const float*)d_in[11];
  const float* a2b1 = (const float*)d_in[12];
  const float* a2w2 = (const float*)d_in[13];
  const float* a2b2 = (const float*)d_in[14];
  float* outf = (float*)d_out;

  // d_out scratch (all dead before conv2 overwrites d_out):
  short* xt     = (short*)d_out;                              // 67,108,864 B
  float* gpart1 = (float*)((char*)d_out + 67108864);          //  2,097,152 B (B*CIN x 256)
  float* gpart2 = (float*)((char*)d_out + 69206016);          //  4,194,304 B (B*COUT x 256)

  char* wsb = (char*)d_ws;
  short* y1t  = (short*)wsb;                                   // 134,217,728 B
  short* wdt  = (short*)(wsb + 134217728);                     //  18,874,368 B
  float* gap1 = (float*)(wsb + 153092096);                     //       8,192 B
  float* gap2 = (float*)(wsb + 153100288);                     //      16,384 B
  float* attn = (float*)(wsb + 153116672);                     //         256 B
  short* zbuf = (short*)(wsb + 153116928);                     //         256 B (zeroed)

  const float gsc = 1.f / (float)HW;

  hipMemsetAsync(zbuf, 0, 256, stream);

  // ---- layer 1 ----
  transpose_bf16_kernel<<<dim3(HW / 64, CIN / 32, B), 256, 0, stream>>>(x, xt, CIN, gpart1);
  gap_reduce_kernel<<<(B * CIN) / 4, 256, 0, stream>>>(gpart1, gap1, gsc, 64);
  fd_attn_kernel<<<B, 64, 0, stream>>>(gap1, CIN, CIN / 4, a1w1, a1b1, a1w2, a1b2, attn);
  fd_synth_t_kernel<<<(B * CIN * COUT) / 256, 256, 0, stream>>>(w1fr, w1fi, attn, wdt, B, COUT, CIN);
  conv_mfma_kernel<128, 0><<<dim3(64, 1, 16), 512, 0, stream>>>(xt, wdt, b1, y1t, nullptr, gpart2, zbuf);

  // ---- layer 2 ----
  gap_reduce_kernel<<<(B * COUT) / 4, 256, 0, stream>>>(gpart2, gap2, gsc, 32);
  fd_attn_kernel<<<B, 64, 0, stream>>>(gap2, COUT, COUT / 4, a2w1, a2b1, a2w2, a2b2, attn);
  fd_synth_t_kernel<<<(B * COUT * COUT) / 256, 256, 0, stream>>>(w2fr, w2fi, attn, wdt, B, COUT, COUT);
  conv_mfma_kernel<256, 1><<<dim3(64, 1, 16), 512, 0, stream>>>(y1t, wdt, b2, nullptr, outf, nullptr, zbuf);
}